// Round 1
// baseline (2576.290 us; speedup 1.0000x reference)
//
#include <hip/hip_runtime.h>
#include <hip/hip_bf16.h>
#include <math.h>

#define NUM_EMB 8192
#define DIM 512
#define NROWS 16384   // 32*512

#define BM 64
#define BN 64
#define BK 32
#define KSPLIT 4
#define KPER (NUM_EMB / KSPLIT)      // 2048
#define NCT (KPER / BN)              // 32 code tiles per block

// ---------- row sum of squares (wave per row) ----------
__global__ __launch_bounds__(256) void rowsumsq_k(const float* __restrict__ a,
                                                  float* __restrict__ out, int nrows)
{
    int gid  = blockIdx.x * blockDim.x + threadIdx.x;
    int row  = gid >> 6;
    int lane = threadIdx.x & 63;
    if (row >= nrows) return;
    const float4* r = (const float4*)(a + (size_t)row * DIM);
    float s = 0.f;
#pragma unroll
    for (int i = lane; i < DIM / 4; i += 64) {
        float4 v = r[i];
        s += v.x * v.x + v.y * v.y + v.z * v.z + v.w * v.w;
    }
#pragma unroll
    for (int off = 32; off > 0; off >>= 1) s += __shfl_down(s, off, 64);
    if (lane == 0) out[row] = s;
}

// ---------- main: tiled dots + running argmin of (e2 - 2*dot) ----------
__global__ __launch_bounds__(256) void dist_argmin_k(const float* __restrict__ x,
    const float* __restrict__ cb, const float* __restrict__ e2,
    float* __restrict__ part_m, int* __restrict__ part_i)
{
    // transposed LDS tiles, stride 68 (=64+4): 16B-aligned float4 rows, 2-way bank aliasing max
    __shared__ __align__(16) float As[BK][BM + 4];
    __shared__ __align__(16) float Bs[BK][BN + 4];
    __shared__ float redv[BM][16];
    __shared__ int   redi[BM][16];

    const int row0 = blockIdx.x * BM;
    const int ks   = blockIdx.y;
    const int cbeg = ks * KPER;
    const int t    = threadIdx.x;
    const int tx   = t & 15;      // code group
    const int ty   = t >> 4;      // row group
    const int ld_d = t & 31;      // staging: d within chunk
    const int ld_r = t >> 5;      // staging: row 0..7 (stride 8)

    float minm[4];
    int   mini[4];
#pragma unroll
    for (int i = 0; i < 4; ++i) { minm[i] = INFINITY; mini[i] = 0; }

    for (int ct = 0; ct < NCT; ++ct) {
        const int c0 = cbeg + ct * BN;
        float acc[4][4];
#pragma unroll
        for (int i = 0; i < 4; ++i)
#pragma unroll
            for (int j = 0; j < 4; ++j) acc[i][j] = 0.f;

        for (int dc = 0; dc < DIM; dc += BK) {
#pragma unroll
            for (int rr = 0; rr < BM; rr += 8)
                As[ld_d][ld_r + rr] = x[(size_t)(row0 + ld_r + rr) * DIM + dc + ld_d];
#pragma unroll
            for (int rr = 0; rr < BN; rr += 8)
                Bs[ld_d][ld_r + rr] = cb[(size_t)(c0 + ld_r + rr) * DIM + dc + ld_d];
            __syncthreads();
#pragma unroll
            for (int d = 0; d < BK; ++d) {
                float4 av = *(const float4*)&As[d][4 * ty];
                float4 bv = *(const float4*)&Bs[d][4 * tx];
                acc[0][0] += av.x * bv.x; acc[0][1] += av.x * bv.y;
                acc[0][2] += av.x * bv.z; acc[0][3] += av.x * bv.w;
                acc[1][0] += av.y * bv.x; acc[1][1] += av.y * bv.y;
                acc[1][2] += av.y * bv.z; acc[1][3] += av.y * bv.w;
                acc[2][0] += av.z * bv.x; acc[2][1] += av.z * bv.y;
                acc[2][2] += av.z * bv.z; acc[2][3] += av.z * bv.w;
                acc[3][0] += av.w * bv.x; acc[3][1] += av.w * bv.y;
                acc[3][2] += av.w * bv.z; acc[3][3] += av.w * bv.w;
            }
            __syncthreads();
        }
        // epilogue: ascending code order + strict < keeps numpy first-occurrence ties
#pragma unroll
        for (int j = 0; j < 4; ++j) {
            const int c = c0 + 4 * tx + j;
            const float e = e2[c];
#pragma unroll
            for (int i = 0; i < 4; ++i) {
                float m = e - 2.f * acc[i][j];
                if (m < minm[i]) { minm[i] = m; mini[i] = c; }
            }
        }
    }

#pragma unroll
    for (int i = 0; i < 4; ++i) {
        redv[4 * ty + i][tx] = minm[i];
        redi[4 * ty + i][tx] = mini[i];
    }
    __syncthreads();
    if (t < BM) {
        float bm = INFINITY; int bi = 0;
#pragma unroll
        for (int c = 0; c < 16; ++c) {   // tx ascending == ascending code ranges
            float v = redv[t][c];
            if (v < bm) { bm = v; bi = redi[t][c]; }
        }
        part_m[(size_t)(row0 + t) * KSPLIT + ks] = bm;
        part_i[(size_t)(row0 + t) * KSPLIT + ks] = bi;
    }
}

// ---------- merge K-splits, emit indices (as float) + min_distances ----------
__global__ __launch_bounds__(256) void merge_k(const float* __restrict__ part_m,
    const int* __restrict__ part_i, const float* __restrict__ x2,
    float* __restrict__ out_idx, float* __restrict__ out_mind, int* __restrict__ idx_ws)
{
    int row = blockIdx.x * blockDim.x + threadIdx.x;
    if (row >= NROWS) return;
    float bm = INFINITY; int bi = 0;
#pragma unroll
    for (int s = 0; s < KSPLIT; ++s) {   // ascending split = ascending code ranges
        float v = part_m[(size_t)row * KSPLIT + s];
        if (v < bm) { bm = v; bi = part_i[(size_t)row * KSPLIT + s]; }
    }
    out_idx[row]  = (float)bi;
    out_mind[row] = x2[row] + bm;
    idx_ws[row]   = bi;
}

// ---------- gather codebook rows + elementwise sum (x-q)^2 ----------
__global__ __launch_bounds__(256) void gather_loss_k(const float* __restrict__ x,
    const float* __restrict__ cb, const int* __restrict__ idx,
    float* __restrict__ outq, float* __restrict__ Ssum)
{
    int gid  = blockIdx.x * blockDim.x + threadIdx.x;
    int row  = gid >> 6;
    int lane = threadIdx.x & 63;
    if (row >= NROWS) return;
    const int k = idx[row];
    const float4* q  = (const float4*)(cb + (size_t)k * DIM);
    const float4* xr = (const float4*)(x + (size_t)row * DIM);
    float4* o = (float4*)(outq + (size_t)row * DIM);
    float s = 0.f;
#pragma unroll
    for (int i = lane; i < DIM / 4; i += 64) {
        float4 qv = q[i], xv = xr[i];
        o[i] = qv;
        float dx = xv.x - qv.x, dy = xv.y - qv.y;
        float dz = xv.z - qv.z, dw = xv.w - qv.w;
        s += dx * dx + dy * dy + dz * dz + dw * dw;
    }
#pragma unroll
    for (int off = 32; off > 0; off >>= 1) s += __shfl_down(s, off, 64);
    if (lane == 0) atomicAdd(Ssum, s);
}

__global__ void init_k(float* S) { *S = 0.f; }

__global__ void finalize_k(const float* __restrict__ S,
                           float* __restrict__ out_loss, float* __restrict__ out_commit)
{
    float s = *S;
    *out_loss   = 0.25f * s + s;   // commit*0.25 + vq (identical values)
    *out_commit = s;
}

extern "C" void kernel_launch(void* const* d_in, const int* in_sizes, int n_in,
                              void* d_out, int out_size, void* d_ws, size_t ws_size,
                              hipStream_t stream)
{
    const float* x  = (const float*)d_in[0];   // [16384, 512]
    const float* cb = (const float*)d_in[1];   // [8192, 512]
    float* out = (float*)d_out;

    float* outq       = out;                           // 8388608
    float* out_loss   = out + 8388608;                 // 1
    float* out_idx    = out + 8388609;                 // 16384
    float* out_mind   = out + 8388609 + 16384;         // 16384
    float* out_commit = out + 8388609 + 2 * 16384;     // 1

    float* wsf  = (float*)d_ws;
    float* S    = wsf;                      // 1 (+15 pad)
    float* e2   = wsf + 16;                 // 8192
    float* x2   = e2 + NUM_EMB;             // 16384
    float* pm   = x2 + NROWS;               // 16384*KSPLIT
    int*   pi   = (int*)(pm + (size_t)NROWS * KSPLIT);   // 16384*KSPLIT
    int*   idxw = pi + (size_t)NROWS * KSPLIT;           // 16384

    init_k<<<1, 1, 0, stream>>>(S);
    rowsumsq_k<<<NUM_EMB / 4, 256, 0, stream>>>(cb, e2, NUM_EMB);
    rowsumsq_k<<<NROWS / 4, 256, 0, stream>>>(x, x2, NROWS);

    dim3 grid(NROWS / BM, KSPLIT);
    dist_argmin_k<<<grid, 256, 0, stream>>>(x, cb, e2, pm, pi);

    merge_k<<<NROWS / 256, 256, 0, stream>>>(pm, pi, x2, out_idx, out_mind, idxw);
    gather_loss_k<<<NROWS / 4, 256, 0, stream>>>(x, cb, idxw, outq, S);
    finalize_k<<<1, 1, 0, stream>>>(S, out_loss, out_commit);
}

// Round 2
// 691.166 us; speedup vs baseline: 3.7275x; 3.7275x over previous
//
#include <hip/hip_runtime.h>
#include <hip/hip_bf16.h>
#include <math.h>

#define NUM_EMB 8192
#define DIM 512
#define NROWS 16384   // 32*512

typedef unsigned short ushort;
typedef unsigned long long ull;
typedef __attribute__((ext_vector_type(8))) short short8;
typedef __attribute__((ext_vector_type(4))) float floatx4;

// ---------------- helpers ----------------
__device__ __forceinline__ ushort f2bf(float f) {
    unsigned u = __float_as_uint(f);
    unsigned r = (u + 0x7fffu + ((u >> 16) & 1u)) >> 16;   // RNE
    return (ushort)r;
}
__device__ __forceinline__ float bf2f(ushort h) {
    return __uint_as_float(((unsigned)h) << 16);
}
__device__ __forceinline__ unsigned fmap(float f) {       // monotone float->uint
    unsigned u = __float_as_uint(f);
    return (u & 0x80000000u) ? ~u : (u | 0x80000000u);
}
__device__ __forceinline__ float funmap(unsigned m) {
    return __uint_as_float((m & 0x80000000u) ? (m ^ 0x80000000u) : ~m);
}
__device__ __forceinline__ void gld16(const void* g, void* l) {
    __builtin_amdgcn_global_load_lds(
        (const __attribute__((address_space(1))) void*)g,
        (__attribute__((address_space(3))) void*)l, 16, 0, 0);
}

// ---------- row sum of squares (wave per row) ----------
__global__ __launch_bounds__(256) void rowsumsq_k(const float* __restrict__ a,
                                                  float* __restrict__ out, int nrows)
{
    int gid  = blockIdx.x * blockDim.x + threadIdx.x;
    int row  = gid >> 6;
    int lane = threadIdx.x & 63;
    if (row >= nrows) return;
    const float4* r = (const float4*)(a + (size_t)row * DIM);
    float s = 0.f;
#pragma unroll
    for (int i = lane; i < DIM / 4; i += 64) {
        float4 v = r[i];
        s += v.x * v.x + v.y * v.y + v.z * v.z + v.w * v.w;
    }
#pragma unroll
    for (int off = 32; off > 0; off >>= 1) s += __shfl_down(s, off, 64);
    if (lane == 0) out[row] = s;
}

// ---------- fp32 -> bf16 hi/lo split ----------
__global__ __launch_bounds__(256) void split_k(const float* __restrict__ src,
    ushort* __restrict__ hi, ushort* __restrict__ lo, int n4)
{
    int i = blockIdx.x * 256 + threadIdx.x;
    if (i >= n4) return;
    float4 v = ((const float4*)src)[i];
    ushort4 h, l;
    h.x = f2bf(v.x); l.x = f2bf(v.x - bf2f(h.x));
    h.y = f2bf(v.y); l.y = f2bf(v.y - bf2f(h.y));
    h.z = f2bf(v.z); l.z = f2bf(v.z - bf2f(h.z));
    h.w = f2bf(v.w); l.w = f2bf(v.w - bf2f(h.w));
    ((ushort4*)hi)[i] = h;
    ((ushort4*)lo)[i] = l;
}

// ---------- init ----------
__global__ __launch_bounds__(256) void init_k(ull* __restrict__ packed, float* __restrict__ S)
{
    int i = blockIdx.x * 256 + threadIdx.x;
    if (i < NROWS) packed[i] = ~0ull;
    if (i == 0) *S = 0.f;
}

// ---------- MFMA distance + argmin ----------
// grid (128, 64): 128x128 tile of rows x codes. 3-pass bf16 split GEMM.
__global__ __launch_bounds__(256, 2) void dist_mfma_k(
    const ushort* __restrict__ xh, const ushort* __restrict__ xl,
    const ushort* __restrict__ ch, const ushort* __restrict__ cl,
    const float* __restrict__ e2, ull* __restrict__ packed)
{
    __shared__ ushort Ah[128 * 32];
    __shared__ ushort Al[128 * 32];
    __shared__ ushort Bh[128 * 32];
    __shared__ ushort Bl[128 * 32];

    const int tid  = threadIdx.x;
    const int lane = tid & 63;
    const int w    = tid >> 6;
    const int wm   = w >> 1, wn = w & 1;
    const int row0 = blockIdx.x * 128;
    const int col0 = blockIdx.y * 128;

    floatx4 acc[4][4];
#pragma unroll
    for (int m = 0; m < 4; ++m)
#pragma unroll
        for (int n = 0; n < 4; ++n) acc[m][n] = (floatx4){0.f, 0.f, 0.f, 0.f};

    // staging chunk map: chunk c (0..511) -> row c>>2, 8-elem group c&3; lds off c*8
    const int c0 = tid, c1 = tid + 256;
    const int r0c = c0 >> 2, s0c = (c0 & 3) * 8;
    const int r1c = c1 >> 2, s1c = (c1 & 3) * 8;
    const int ga0 = (row0 + r0c) * DIM + s0c;   // + dk
    const int ga1 = (row0 + r1c) * DIM + s1c;
    const int gb0 = (col0 + r0c) * DIM + s0c;
    const int gb1 = (col0 + r1c) * DIM + s1c;
    const int l0 = c0 * 8, l1 = c1 * 8;

    const int fr = (lane & 15) * 32 + (lane >> 4) * 8;   // fragment base (elems)

    for (int kk = 0; kk < 16; ++kk) {
        const int dk = kk * 32;
        __syncthreads();
        gld16(&xh[ga0 + dk], &Ah[l0]);  gld16(&xh[ga1 + dk], &Ah[l1]);
        gld16(&xl[ga0 + dk], &Al[l0]);  gld16(&xl[ga1 + dk], &Al[l1]);
        gld16(&ch[gb0 + dk], &Bh[l0]);  gld16(&ch[gb1 + dk], &Bh[l1]);
        gld16(&cl[gb0 + dk], &Bl[l0]);  gld16(&cl[gb1 + dk], &Bl[l1]);
        __syncthreads();

        short8 ah[4], al[4], bh[4], bl[4];
#pragma unroll
        for (int m = 0; m < 4; ++m) {
            const int o = (wm * 64 + m * 16) * 32 + fr;
            ah[m] = *(const short8*)&Ah[o];
            al[m] = *(const short8*)&Al[o];
        }
#pragma unroll
        for (int n = 0; n < 4; ++n) {
            const int o = (wn * 64 + n * 16) * 32 + fr;
            bh[n] = *(const short8*)&Bh[o];
            bl[n] = *(const short8*)&Bl[o];
        }
#pragma unroll
        for (int m = 0; m < 4; ++m)
#pragma unroll
            for (int n = 0; n < 4; ++n) {
                acc[m][n] = __builtin_amdgcn_mfma_f32_16x16x32_bf16(ah[m], bh[n], acc[m][n], 0, 0, 0);
                acc[m][n] = __builtin_amdgcn_mfma_f32_16x16x32_bf16(ah[m], bl[n], acc[m][n], 0, 0, 0);
                acc[m][n] = __builtin_amdgcn_mfma_f32_16x16x32_bf16(al[m], bh[n], acc[m][n], 0, 0, 0);
            }
    }

    // epilogue: v = e2[c] - 2*dot ; argmin with first-occurrence tie-break
    float e2v[4];
    int   cidx[4];
#pragma unroll
    for (int n = 0; n < 4; ++n) {
        cidx[n] = col0 + wn * 64 + n * 16 + (lane & 15);
        e2v[n]  = e2[cidx[n]];
    }
#pragma unroll
    for (int m = 0; m < 4; ++m) {
#pragma unroll
        for (int r = 0; r < 4; ++r) {
            float bv = INFINITY; int bi = 0x7fffffff;
#pragma unroll
            for (int n = 0; n < 4; ++n) {        // ascending code order
                float v = e2v[n] - 2.f * acc[m][n][r];
                if (v < bv) { bv = v; bi = cidx[n]; }
            }
#pragma unroll
            for (int mk = 1; mk < 16; mk <<= 1) {  // 16-lane butterfly (same quad group)
                float ov = __shfl_xor(bv, mk, 64);
                int   oi = __shfl_xor(bi, mk, 64);
                if (ov < bv || (ov == bv && oi < bi)) { bv = ov; bi = oi; }
            }
            if ((lane & 15) == 0) {
                int grow = row0 + wm * 64 + m * 16 + (lane >> 4) * 4 + r;
                ull pack = ((ull)fmap(bv) << 32) | (unsigned)bi;
                atomicMin(&packed[grow], pack);
            }
        }
    }
}

// ---------- merge: unpack -> indices + min_distances ----------
__global__ __launch_bounds__(256) void merge_k(const ull* __restrict__ packed,
    const float* __restrict__ x2, float* __restrict__ out_idx,
    float* __restrict__ out_mind, int* __restrict__ idx_ws)
{
    int row = blockIdx.x * blockDim.x + threadIdx.x;
    if (row >= NROWS) return;
    ull p = packed[row];
    int bi = (int)(p & 0xffffffffull);
    float m = funmap((unsigned)(p >> 32));
    out_idx[row]  = (float)bi;
    out_mind[row] = x2[row] + m;
    idx_ws[row]   = bi;
}

// ---------- gather codebook rows + elementwise sum (x-q)^2 ----------
__global__ __launch_bounds__(256) void gather_loss_k(const float* __restrict__ x,
    const float* __restrict__ cb, const int* __restrict__ idx,
    float* __restrict__ outq, float* __restrict__ Ssum)
{
    int gid  = blockIdx.x * blockDim.x + threadIdx.x;
    int row  = gid >> 6;
    int lane = threadIdx.x & 63;
    if (row >= NROWS) return;
    const int k = idx[row];
    const float4* q  = (const float4*)(cb + (size_t)k * DIM);
    const float4* xr = (const float4*)(x + (size_t)row * DIM);
    float4* o = (float4*)(outq + (size_t)row * DIM);
    float s = 0.f;
#pragma unroll
    for (int i = lane; i < DIM / 4; i += 64) {
        float4 qv = q[i], xv = xr[i];
        o[i] = qv;
        float dx = xv.x - qv.x, dy = xv.y - qv.y;
        float dz = xv.z - qv.z, dw = xv.w - qv.w;
        s += dx * dx + dy * dy + dz * dz + dw * dw;
    }
#pragma unroll
    for (int off = 32; off > 0; off >>= 1) s += __shfl_down(s, off, 64);
    if (lane == 0) atomicAdd(Ssum, s);
}

__global__ void finalize_k(const float* __restrict__ S,
                           float* __restrict__ out_loss, float* __restrict__ out_commit)
{
    float s = *S;
    *out_loss   = 0.25f * s + s;
    *out_commit = s;
}

// ================= fallback (round-1 fp32 path) =================
#define BM 64
#define BN 64
#define BK 32
#define KSPLIT 4
#define KPER (NUM_EMB / KSPLIT)
#define NCT (KPER / BN)

__global__ __launch_bounds__(256) void dist_argmin_old_k(const float* __restrict__ x,
    const float* __restrict__ cb, const float* __restrict__ e2,
    float* __restrict__ part_m, int* __restrict__ part_i)
{
    __shared__ __align__(16) float As[BK][BM + 4];
    __shared__ __align__(16) float Bs[BK][BN + 4];
    __shared__ float redv[BM][16];
    __shared__ int   redi[BM][16];

    const int row0 = blockIdx.x * BM;
    const int ks   = blockIdx.y;
    const int cbeg = ks * KPER;
    const int t    = threadIdx.x;
    const int tx   = t & 15;
    const int ty   = t >> 4;
    const int ld_d = t & 31;
    const int ld_r = t >> 5;

    float minm[4]; int mini[4];
#pragma unroll
    for (int i = 0; i < 4; ++i) { minm[i] = INFINITY; mini[i] = 0; }

    for (int ct = 0; ct < NCT; ++ct) {
        const int c0 = cbeg + ct * BN;
        float acc[4][4];
#pragma unroll
        for (int i = 0; i < 4; ++i)
#pragma unroll
            for (int j = 0; j < 4; ++j) acc[i][j] = 0.f;
        for (int dc = 0; dc < DIM; dc += BK) {
#pragma unroll
            for (int rr = 0; rr < BM; rr += 8)
                As[ld_d][ld_r + rr] = x[(size_t)(row0 + ld_r + rr) * DIM + dc + ld_d];
#pragma unroll
            for (int rr = 0; rr < BN; rr += 8)
                Bs[ld_d][ld_r + rr] = cb[(size_t)(c0 + ld_r + rr) * DIM + dc + ld_d];
            __syncthreads();
#pragma unroll
            for (int d = 0; d < BK; ++d) {
                float4 av = *(const float4*)&As[d][4 * ty];
                float4 bv = *(const float4*)&Bs[d][4 * tx];
                acc[0][0] += av.x * bv.x; acc[0][1] += av.x * bv.y;
                acc[0][2] += av.x * bv.z; acc[0][3] += av.x * bv.w;
                acc[1][0] += av.y * bv.x; acc[1][1] += av.y * bv.y;
                acc[1][2] += av.y * bv.z; acc[1][3] += av.y * bv.w;
                acc[2][0] += av.z * bv.x; acc[2][1] += av.z * bv.y;
                acc[2][2] += av.z * bv.z; acc[2][3] += av.z * bv.w;
                acc[3][0] += av.w * bv.x; acc[3][1] += av.w * bv.y;
                acc[3][2] += av.w * bv.z; acc[3][3] += av.w * bv.w;
            }
            __syncthreads();
        }
#pragma unroll
        for (int j = 0; j < 4; ++j) {
            const int c = c0 + 4 * tx + j;
            const float e = e2[c];
#pragma unroll
            for (int i = 0; i < 4; ++i) {
                float m = e - 2.f * acc[i][j];
                if (m < minm[i]) { minm[i] = m; mini[i] = c; }
            }
        }
    }
#pragma unroll
    for (int i = 0; i < 4; ++i) {
        redv[4 * ty + i][tx] = minm[i];
        redi[4 * ty + i][tx] = mini[i];
    }
    __syncthreads();
    if (t < BM) {
        float bm = INFINITY; int bi = 0;
#pragma unroll
        for (int c = 0; c < 16; ++c) {
            float v = redv[t][c];
            if (v < bm) { bm = v; bi = redi[t][c]; }
        }
        part_m[(size_t)(row0 + t) * KSPLIT + ks] = bm;
        part_i[(size_t)(row0 + t) * KSPLIT + ks] = bi;
    }
}

__global__ __launch_bounds__(256) void merge_old_k(const float* __restrict__ part_m,
    const int* __restrict__ part_i, const float* __restrict__ x2,
    float* __restrict__ out_idx, float* __restrict__ out_mind, int* __restrict__ idx_ws)
{
    int row = blockIdx.x * blockDim.x + threadIdx.x;
    if (row >= NROWS) return;
    float bm = INFINITY; int bi = 0;
#pragma unroll
    for (int s = 0; s < KSPLIT; ++s) {
        float v = part_m[(size_t)row * KSPLIT + s];
        if (v < bm) { bm = v; bi = part_i[(size_t)row * KSPLIT + s]; }
    }
    out_idx[row]  = (float)bi;
    out_mind[row] = x2[row] + bm;
    idx_ws[row]   = bi;
}

__global__ void init_old_k(float* S) { *S = 0.f; }

// ================= launch =================
extern "C" void kernel_launch(void* const* d_in, const int* in_sizes, int n_in,
                              void* d_out, int out_size, void* d_ws, size_t ws_size,
                              hipStream_t stream)
{
    const float* x  = (const float*)d_in[0];   // [16384, 512]
    const float* cb = (const float*)d_in[1];   // [8192, 512]
    float* out = (float*)d_out;

    float* outq       = out;
    float* out_loss   = out + 8388608;
    float* out_idx    = out + 8388609;
    float* out_mind   = out + 8388609 + 16384;
    float* out_commit = out + 8388609 + 2 * 16384;

    char* ws = (char*)d_ws;
    // common small blocks
    float* S   = (float*)ws;                    ws += 64;
    float* e2  = (float*)ws;                    ws += NUM_EMB * 4;
    float* x2  = (float*)ws;                    ws += NROWS * 4;
    ull*  packed = (ull*)ws;                    ws += NROWS * 8;
    int*  idxw   = (int*)ws;                    ws += NROWS * 4;
    ushort* xh = (ushort*)ws;                   ws += (size_t)NROWS * DIM * 2;
    ushort* xl = (ushort*)ws;                   ws += (size_t)NROWS * DIM * 2;
    ushort* ch = (ushort*)ws;                   ws += (size_t)NUM_EMB * DIM * 2;
    ushort* cl = (ushort*)ws;                   ws += (size_t)NUM_EMB * DIM * 2;
    size_t need_fast = (size_t)(ws - (char*)d_ws);

    rowsumsq_k<<<NUM_EMB / 4, 256, 0, stream>>>(cb, e2, NUM_EMB);
    rowsumsq_k<<<NROWS / 4, 256, 0, stream>>>(x, x2, NROWS);

    if (ws_size >= need_fast) {
        init_k<<<NROWS / 256, 256, 0, stream>>>(packed, S);
        split_k<<<(NROWS * DIM / 4 + 255) / 256, 256, 0, stream>>>(x, xh, xl, NROWS * DIM / 4);
        split_k<<<(NUM_EMB * DIM / 4 + 255) / 256, 256, 0, stream>>>(cb, ch, cl, NUM_EMB * DIM / 4);
        dim3 grid(NROWS / 128, NUM_EMB / 128);
        dist_mfma_k<<<grid, 256, 0, stream>>>(xh, xl, ch, cl, e2, packed);
        merge_k<<<NROWS / 256, 256, 0, stream>>>(packed, x2, out_idx, out_mind, idxw);
    } else {
        // fallback: round-1 fp32 path (small ws)
        float* pm = (float*)((char*)d_ws + 64 + NUM_EMB * 4 + NROWS * 4);
        int*   pi = (int*)(pm + (size_t)NROWS * KSPLIT);
        int*   idxw2 = pi + (size_t)NROWS * KSPLIT;
        idxw = idxw2;
        init_old_k<<<1, 1, 0, stream>>>(S);
        dim3 grid(NROWS / BM, KSPLIT);
        dist_argmin_old_k<<<grid, 256, 0, stream>>>(x, cb, e2, pm, pi);
        merge_old_k<<<NROWS / 256, 256, 0, stream>>>(pm, pi, x2, out_idx, out_mind, idxw);
    }

    gather_loss_k<<<NROWS / 4, 256, 0, stream>>>(x, cb, idxw, outq, S);
    finalize_k<<<1, 1, 0, stream>>>(S, out_loss, out_commit);
}

// Round 3
// 494.919 us; speedup vs baseline: 5.2055x; 1.3965x over previous
//
#include <hip/hip_runtime.h>
#include <hip/hip_bf16.h>
#include <math.h>

#define NUM_EMB 8192
#define DIM 512
#define NROWS 16384   // 32*512
#define NPART 4096    // gather_loss partial sums (one per block)

typedef unsigned short ushort;
typedef unsigned long long ull;
typedef __attribute__((ext_vector_type(8))) short short8;
typedef __attribute__((ext_vector_type(4))) float floatx4;

// ---------------- helpers ----------------
__device__ __forceinline__ ushort f2bf(float f) {
    unsigned u = __float_as_uint(f);
    unsigned r = (u + 0x7fffu + ((u >> 16) & 1u)) >> 16;   // RNE
    return (ushort)r;
}
__device__ __forceinline__ float bf2f(ushort h) {
    return __uint_as_float(((unsigned)h) << 16);
}
__device__ __forceinline__ unsigned fmap(float f) {       // monotone float->uint
    unsigned u = __float_as_uint(f);
    return (u & 0x80000000u) ? ~u : (u | 0x80000000u);
}
__device__ __forceinline__ float funmap(unsigned m) {
    return __uint_as_float((m & 0x80000000u) ? (m ^ 0x80000000u) : ~m);
}
__device__ __forceinline__ void gld16(const void* g, void* l) {
    __builtin_amdgcn_global_load_lds(
        (const __attribute__((address_space(1))) void*)g,
        (__attribute__((address_space(3))) void*)l, 16, 0, 0);
}

// ---------- fused: fp32 -> bf16 hi/lo split + row sum of squares ----------
// one wave per row
__global__ __launch_bounds__(256) void split_rss_k(const float* __restrict__ src,
    ushort* __restrict__ hi, ushort* __restrict__ lo, float* __restrict__ ss, int nrows)
{
    int gid  = blockIdx.x * blockDim.x + threadIdx.x;
    int row  = gid >> 6;
    int lane = threadIdx.x & 63;
    if (row >= nrows) return;
    const float4* r = (const float4*)(src + (size_t)row * DIM);
    ushort4* h4 = (ushort4*)(hi + (size_t)row * DIM);
    ushort4* l4 = (ushort4*)(lo + (size_t)row * DIM);
    float s = 0.f;
#pragma unroll
    for (int i = lane; i < DIM / 4; i += 64) {
        float4 v = r[i];
        s += v.x * v.x + v.y * v.y + v.z * v.z + v.w * v.w;
        ushort4 h, l;
        h.x = f2bf(v.x); l.x = f2bf(v.x - bf2f(h.x));
        h.y = f2bf(v.y); l.y = f2bf(v.y - bf2f(h.y));
        h.z = f2bf(v.z); l.z = f2bf(v.z - bf2f(h.z));
        h.w = f2bf(v.w); l.w = f2bf(v.w - bf2f(h.w));
        h4[i] = h; l4[i] = l;
    }
#pragma unroll
    for (int off = 32; off > 0; off >>= 1) s += __shfl_down(s, off, 64);
    if (lane == 0) ss[row] = s;
}

// ---------- init ----------
__global__ __launch_bounds__(256) void init_k(ull* __restrict__ packed)
{
    int i = blockIdx.x * 256 + threadIdx.x;
    if (i < NROWS) packed[i] = ~0ull;
}

// ---------- MFMA distance + argmin ----------
// grid (128, 64): 128x128 tile of rows x codes. 3-pass bf16 split GEMM.
__global__ __launch_bounds__(256, 4) void dist_mfma_k(
    const ushort* __restrict__ xh, const ushort* __restrict__ xl,
    const ushort* __restrict__ ch, const ushort* __restrict__ cl,
    const float* __restrict__ e2, ull* __restrict__ packed)
{
    __shared__ ushort Ah[128 * 32];
    __shared__ ushort Al[128 * 32];
    __shared__ ushort Bh[128 * 32];
    __shared__ ushort Bl[128 * 32];

    const int tid  = threadIdx.x;
    const int lane = tid & 63;
    const int w    = tid >> 6;
    const int wm   = w >> 1, wn = w & 1;
    const int row0 = blockIdx.x * 128;
    const int col0 = blockIdx.y * 128;

    floatx4 acc[4][4];
#pragma unroll
    for (int m = 0; m < 4; ++m)
#pragma unroll
        for (int n = 0; n < 4; ++n) acc[m][n] = (floatx4){0.f, 0.f, 0.f, 0.f};

    // staging chunk map: chunk c (0..511) -> row c>>2, 8-elem group c&3; lds off c*8
    const int c0 = tid, c1 = tid + 256;
    const int r0c = c0 >> 2, s0c = (c0 & 3) * 8;
    const int r1c = c1 >> 2, s1c = (c1 & 3) * 8;
    const int ga0 = (row0 + r0c) * DIM + s0c;   // + dk
    const int ga1 = (row0 + r1c) * DIM + s1c;
    const int gb0 = (col0 + r0c) * DIM + s0c;
    const int gb1 = (col0 + r1c) * DIM + s1c;
    const int l0 = c0 * 8, l1 = c1 * 8;

    const int fr = (lane & 15) * 32 + (lane >> 4) * 8;   // fragment base (elems)

    for (int kk = 0; kk < 16; ++kk) {
        const int dk = kk * 32;
        __syncthreads();
        gld16(&xh[ga0 + dk], &Ah[l0]);  gld16(&xh[ga1 + dk], &Ah[l1]);
        gld16(&xl[ga0 + dk], &Al[l0]);  gld16(&xl[ga1 + dk], &Al[l1]);
        gld16(&ch[gb0 + dk], &Bh[l0]);  gld16(&ch[gb1 + dk], &Bh[l1]);
        gld16(&cl[gb0 + dk], &Bl[l0]);  gld16(&cl[gb1 + dk], &Bl[l1]);
        __syncthreads();

        short8 ah[4], al[4], bh[4], bl[4];
#pragma unroll
        for (int m = 0; m < 4; ++m) {
            const int o = (wm * 64 + m * 16) * 32 + fr;
            ah[m] = *(const short8*)&Ah[o];
            al[m] = *(const short8*)&Al[o];
        }
#pragma unroll
        for (int n = 0; n < 4; ++n) {
            const int o = (wn * 64 + n * 16) * 32 + fr;
            bh[n] = *(const short8*)&Bh[o];
            bl[n] = *(const short8*)&Bl[o];
        }
#pragma unroll
        for (int m = 0; m < 4; ++m)
#pragma unroll
            for (int n = 0; n < 4; ++n) {
                acc[m][n] = __builtin_amdgcn_mfma_f32_16x16x32_bf16(ah[m], bh[n], acc[m][n], 0, 0, 0);
                acc[m][n] = __builtin_amdgcn_mfma_f32_16x16x32_bf16(ah[m], bl[n], acc[m][n], 0, 0, 0);
                acc[m][n] = __builtin_amdgcn_mfma_f32_16x16x32_bf16(al[m], bh[n], acc[m][n], 0, 0, 0);
            }
    }

    // epilogue: v = e2[c] - 2*dot ; argmin with first-occurrence tie-break
    float e2v[4];
    int   cidx[4];
#pragma unroll
    for (int n = 0; n < 4; ++n) {
        cidx[n] = col0 + wn * 64 + n * 16 + (lane & 15);
        e2v[n]  = e2[cidx[n]];
    }
#pragma unroll
    for (int m = 0; m < 4; ++m) {
#pragma unroll
        for (int r = 0; r < 4; ++r) {
            float bv = INFINITY; int bi = 0x7fffffff;
#pragma unroll
            for (int n = 0; n < 4; ++n) {        // ascending code order
                float v = e2v[n] - 2.f * acc[m][n][r];
                if (v < bv) { bv = v; bi = cidx[n]; }
            }
#pragma unroll
            for (int mk = 1; mk < 16; mk <<= 1) {  // 16-lane butterfly (same quad group)
                float ov = __shfl_xor(bv, mk, 64);
                int   oi = __shfl_xor(bi, mk, 64);
                if (ov < bv || (ov == bv && oi < bi)) { bv = ov; bi = oi; }
            }
            if ((lane & 15) == 0) {
                int grow = row0 + wm * 64 + m * 16 + (lane >> 4) * 4 + r;
                ull pack = ((ull)fmap(bv) << 32) | (unsigned)bi;
                atomicMin(&packed[grow], pack);
            }
        }
    }
}

// ---------- merge: unpack -> indices + min_distances ----------
__global__ __launch_bounds__(256) void merge_k(const ull* __restrict__ packed,
    const float* __restrict__ x2, float* __restrict__ out_idx,
    float* __restrict__ out_mind, int* __restrict__ idx_ws)
{
    int row = blockIdx.x * blockDim.x + threadIdx.x;
    if (row >= NROWS) return;
    ull p = packed[row];
    int bi = (int)(p & 0xffffffffull);
    float m = funmap((unsigned)(p >> 32));
    out_idx[row]  = (float)bi;
    out_mind[row] = x2[row] + m;
    idx_ws[row]   = bi;
}

// ---------- gather codebook rows + per-block partial sum of (x-q)^2 ----------
// NO same-address atomics: one partials[] store per block (was 16384 atomicAdds
// to a single word = ~240 us of L2 serialization).
__global__ __launch_bounds__(256) void gather_loss_k(const float* __restrict__ x,
    const float* __restrict__ cb, const int* __restrict__ idx,
    float* __restrict__ outq, float* __restrict__ partials)
{
    __shared__ float ps[4];
    int gid  = blockIdx.x * blockDim.x + threadIdx.x;
    int row  = gid >> 6;
    int lane = threadIdx.x & 63;
    int w    = threadIdx.x >> 6;
    float s = 0.f;
    if (row < NROWS) {
        const int k = idx[row];
        const float4* q  = (const float4*)(cb + (size_t)k * DIM);
        const float4* xr = (const float4*)(x + (size_t)row * DIM);
        float4* o = (float4*)(outq + (size_t)row * DIM);
#pragma unroll
        for (int i = lane; i < DIM / 4; i += 64) {
            float4 qv = q[i], xv = xr[i];
            o[i] = qv;
            float dx = xv.x - qv.x, dy = xv.y - qv.y;
            float dz = xv.z - qv.z, dw = xv.w - qv.w;
            s += dx * dx + dy * dy + dz * dz + dw * dw;
        }
    }
#pragma unroll
    for (int off = 32; off > 0; off >>= 1) s += __shfl_down(s, off, 64);
    if (lane == 0) ps[w] = s;
    __syncthreads();
    if (threadIdx.x == 0) partials[blockIdx.x] = ps[0] + ps[1] + ps[2] + ps[3];
}

// ---------- final reduction of partials -> loss outputs ----------
__global__ __launch_bounds__(256) void finalize_k(const float* __restrict__ partials,
    float* __restrict__ out_loss, float* __restrict__ out_commit)
{
    __shared__ float ps[4];
    int t = threadIdx.x, lane = t & 63, w = t >> 6;
    float s = 0.f;
#pragma unroll
    for (int i = 0; i < NPART / 256; ++i) s += partials[t + 256 * i];
#pragma unroll
    for (int off = 32; off > 0; off >>= 1) s += __shfl_down(s, off, 64);
    if (lane == 0) ps[w] = s;
    __syncthreads();
    if (t == 0) {
        float tot = ps[0] + ps[1] + ps[2] + ps[3];
        *out_loss   = 0.25f * tot + tot;
        *out_commit = tot;
    }
}

// ================= fallback (fp32 path, small ws) =================
#define BM 64
#define BN 64
#define BK 32
#define KSPLIT 4
#define KPER (NUM_EMB / KSPLIT)
#define NCT (KPER / BN)

__global__ __launch_bounds__(256) void rowsumsq_k(const float* __restrict__ a,
                                                  float* __restrict__ out, int nrows)
{
    int gid  = blockIdx.x * blockDim.x + threadIdx.x;
    int row  = gid >> 6;
    int lane = threadIdx.x & 63;
    if (row >= nrows) return;
    const float4* r = (const float4*)(a + (size_t)row * DIM);
    float s = 0.f;
#pragma unroll
    for (int i = lane; i < DIM / 4; i += 64) {
        float4 v = r[i];
        s += v.x * v.x + v.y * v.y + v.z * v.z + v.w * v.w;
    }
#pragma unroll
    for (int off = 32; off > 0; off >>= 1) s += __shfl_down(s, off, 64);
    if (lane == 0) out[row] = s;
}

__global__ __launch_bounds__(256) void dist_argmin_old_k(const float* __restrict__ x,
    const float* __restrict__ cb, const float* __restrict__ e2,
    float* __restrict__ part_m, int* __restrict__ part_i)
{
    __shared__ __align__(16) float As[BK][BM + 4];
    __shared__ __align__(16) float Bs[BK][BN + 4];
    __shared__ float redv[BM][16];
    __shared__ int   redi[BM][16];

    const int row0 = blockIdx.x * BM;
    const int ks   = blockIdx.y;
    const int cbeg = ks * KPER;
    const int t    = threadIdx.x;
    const int tx   = t & 15;
    const int ty   = t >> 4;
    const int ld_d = t & 31;
    const int ld_r = t >> 5;

    float minm[4]; int mini[4];
#pragma unroll
    for (int i = 0; i < 4; ++i) { minm[i] = INFINITY; mini[i] = 0; }

    for (int ct = 0; ct < NCT; ++ct) {
        const int c0 = cbeg + ct * BN;
        float acc[4][4];
#pragma unroll
        for (int i = 0; i < 4; ++i)
#pragma unroll
            for (int j = 0; j < 4; ++j) acc[i][j] = 0.f;
        for (int dc = 0; dc < DIM; dc += BK) {
#pragma unroll
            for (int rr = 0; rr < BM; rr += 8)
                As[ld_d][ld_r + rr] = x[(size_t)(row0 + ld_r + rr) * DIM + dc + ld_d];
#pragma unroll
            for (int rr = 0; rr < BN; rr += 8)
                Bs[ld_d][ld_r + rr] = cb[(size_t)(c0 + ld_r + rr) * DIM + dc + ld_d];
            __syncthreads();
#pragma unroll
            for (int d = 0; d < BK; ++d) {
                float4 av = *(const float4*)&As[d][4 * ty];
                float4 bv = *(const float4*)&Bs[d][4 * tx];
                acc[0][0] += av.x * bv.x; acc[0][1] += av.x * bv.y;
                acc[0][2] += av.x * bv.z; acc[0][3] += av.x * bv.w;
                acc[1][0] += av.y * bv.x; acc[1][1] += av.y * bv.y;
                acc[1][2] += av.y * bv.z; acc[1][3] += av.y * bv.w;
                acc[2][0] += av.z * bv.x; acc[2][1] += av.z * bv.y;
                acc[2][2] += av.z * bv.z; acc[2][3] += av.z * bv.w;
                acc[3][0] += av.w * bv.x; acc[3][1] += av.w * bv.y;
                acc[3][2] += av.w * bv.z; acc[3][3] += av.w * bv.w;
            }
            __syncthreads();
        }
#pragma unroll
        for (int j = 0; j < 4; ++j) {
            const int c = c0 + 4 * tx + j;
            const float e = e2[c];
#pragma unroll
            for (int i = 0; i < 4; ++i) {
                float m = e - 2.f * acc[i][j];
                if (m < minm[i]) { minm[i] = m; mini[i] = c; }
            }
        }
    }
#pragma unroll
    for (int i = 0; i < 4; ++i) {
        redv[4 * ty + i][tx] = minm[i];
        redi[4 * ty + i][tx] = mini[i];
    }
    __syncthreads();
    if (t < BM) {
        float bm = INFINITY; int bi = 0;
#pragma unroll
        for (int c = 0; c < 16; ++c) {
            float v = redv[t][c];
            if (v < bm) { bm = v; bi = redi[t][c]; }
        }
        part_m[(size_t)(row0 + t) * KSPLIT + ks] = bm;
        part_i[(size_t)(row0 + t) * KSPLIT + ks] = bi;
    }
}

__global__ __launch_bounds__(256) void merge_old_k(const float* __restrict__ part_m,
    const int* __restrict__ part_i, const float* __restrict__ x2,
    float* __restrict__ out_idx, float* __restrict__ out_mind, int* __restrict__ idx_ws)
{
    int row = blockIdx.x * blockDim.x + threadIdx.x;
    if (row >= NROWS) return;
    float bm = INFINITY; int bi = 0;
#pragma unroll
    for (int s = 0; s < KSPLIT; ++s) {
        float v = part_m[(size_t)row * KSPLIT + s];
        if (v < bm) { bm = v; bi = part_i[(size_t)row * KSPLIT + s]; }
    }
    out_idx[row]  = (float)bi;
    out_mind[row] = x2[row] + bm;
    idx_ws[row]   = bi;
}

// ================= launch =================
extern "C" void kernel_launch(void* const* d_in, const int* in_sizes, int n_in,
                              void* d_out, int out_size, void* d_ws, size_t ws_size,
                              hipStream_t stream)
{
    const float* x  = (const float*)d_in[0];   // [16384, 512]
    const float* cb = (const float*)d_in[1];   // [8192, 512]
    float* out = (float*)d_out;

    float* outq       = out;
    float* out_loss   = out + 8388608;
    float* out_idx    = out + 8388609;
    float* out_mind   = out + 8388609 + 16384;
    float* out_commit = out + 8388609 + 2 * 16384;

    char* ws = (char*)d_ws;
    float* e2      = (float*)ws;   ws += NUM_EMB * 4;
    float* x2      = (float*)ws;   ws += NROWS * 4;
    ull*   packed  = (ull*)ws;     ws += NROWS * 8;
    int*   idxw    = (int*)ws;     ws += NROWS * 4;
    float* partials= (float*)ws;   ws += NPART * 4;
    ushort* xh = (ushort*)ws;      ws += (size_t)NROWS * DIM * 2;
    ushort* xl = (ushort*)ws;      ws += (size_t)NROWS * DIM * 2;
    ushort* ch = (ushort*)ws;      ws += (size_t)NUM_EMB * DIM * 2;
    ushort* cl = (ushort*)ws;      ws += (size_t)NUM_EMB * DIM * 2;
    size_t need_fast = (size_t)(ws - (char*)d_ws);

    if (ws_size >= need_fast) {
        init_k<<<NROWS / 256, 256, 0, stream>>>(packed);
        split_rss_k<<<NROWS / 4, 256, 0, stream>>>(x, xh, xl, x2, NROWS);
        split_rss_k<<<NUM_EMB / 4, 256, 0, stream>>>(cb, ch, cl, e2, NUM_EMB);
        dim3 grid(NROWS / 128, NUM_EMB / 128);
        dist_mfma_k<<<grid, 256, 0, stream>>>(xh, xl, ch, cl, e2, packed);
        merge_k<<<NROWS / 256, 256, 0, stream>>>(packed, x2, out_idx, out_mind, idxw);
    } else {
        // fallback: fp32 path (small ws)
        rowsumsq_k<<<NUM_EMB / 4, 256, 0, stream>>>(cb, e2, NUM_EMB);
        rowsumsq_k<<<NROWS / 4, 256, 0, stream>>>(x, x2, NROWS);
        float* pm = (float*)((char*)d_ws + NUM_EMB * 4 + NROWS * 4);
        int*   pi = (int*)(pm + (size_t)NROWS * KSPLIT);
        int*   idxw2 = pi + (size_t)NROWS * KSPLIT;
        float* partials2 = (float*)(idxw2 + NROWS);
        idxw = idxw2; partials = partials2;
        dim3 grid(NROWS / BM, KSPLIT);
        dist_argmin_old_k<<<grid, 256, 0, stream>>>(x, cb, e2, pm, pi);
        merge_old_k<<<NROWS / 256, 256, 0, stream>>>(pm, pi, x2, out_idx, out_mind, idxw);
    }

    gather_loss_k<<<NROWS / 4, 256, 0, stream>>>(x, cb, idxw, outq, partials);
    finalize_k<<<1, 256, 0, stream>>>(partials, out_loss, out_commit);
}

// Round 4
// 483.240 us; speedup vs baseline: 5.3313x; 1.0242x over previous
//
#include <hip/hip_runtime.h>
#include <hip/hip_bf16.h>
#include <math.h>

#define NUM_EMB 8192
#define DIM 512
#define NROWS 16384   // 32*512
#define NPART 4096    // gather_loss partial sums (one per block)

typedef unsigned short ushort;
typedef unsigned long long ull;
typedef __attribute__((ext_vector_type(8))) short short8;
typedef __attribute__((ext_vector_type(4))) float floatx4;

// ---------------- helpers ----------------
__device__ __forceinline__ ushort f2bf(float f) {
    unsigned u = __float_as_uint(f);
    unsigned r = (u + 0x7fffu + ((u >> 16) & 1u)) >> 16;   // RNE
    return (ushort)r;
}
__device__ __forceinline__ float bf2f(ushort h) {
    return __uint_as_float(((unsigned)h) << 16);
}
__device__ __forceinline__ unsigned fmap(float f) {       // monotone float->uint
    unsigned u = __float_as_uint(f);
    return (u & 0x80000000u) ? ~u : (u | 0x80000000u);
}
__device__ __forceinline__ float funmap(unsigned m) {
    return __uint_as_float((m & 0x80000000u) ? (m ^ 0x80000000u) : ~m);
}
__device__ __forceinline__ void gld16(const void* g, void* l) {
    __builtin_amdgcn_global_load_lds(
        (const __attribute__((address_space(1))) void*)g,
        (__attribute__((address_space(3))) void*)l, 16, 0, 0);
}

// ---------- fused: fp32 -> bf16 hi/lo split + row sum of squares (+packed init) ----------
// one wave per row
__global__ __launch_bounds__(256) void split_rss_k(const float* __restrict__ src,
    ushort* __restrict__ hi, ushort* __restrict__ lo, float* __restrict__ ss,
    ull* __restrict__ packed, int nrows)
{
    int gid  = blockIdx.x * blockDim.x + threadIdx.x;
    int row  = gid >> 6;
    int lane = threadIdx.x & 63;
    if (row >= nrows) return;
    const float4* r = (const float4*)(src + (size_t)row * DIM);
    ushort4* h4 = (ushort4*)(hi + (size_t)row * DIM);
    ushort4* l4 = (ushort4*)(lo + (size_t)row * DIM);
    float s = 0.f;
#pragma unroll
    for (int i = lane; i < DIM / 4; i += 64) {
        float4 v = r[i];
        s += v.x * v.x + v.y * v.y + v.z * v.z + v.w * v.w;
        ushort4 h, l;
        h.x = f2bf(v.x); l.x = f2bf(v.x - bf2f(h.x));
        h.y = f2bf(v.y); l.y = f2bf(v.y - bf2f(h.y));
        h.z = f2bf(v.z); l.z = f2bf(v.z - bf2f(h.z));
        h.w = f2bf(v.w); l.w = f2bf(v.w - bf2f(h.w));
        h4[i] = h; l4[i] = l;
    }
#pragma unroll
    for (int off = 32; off > 0; off >>= 1) s += __shfl_down(s, off, 64);
    if (lane == 0) {
        ss[row] = s;
        if (packed) packed[row] = ~0ull;   // fused init (x-pass only)
    }
}

// ---------- MFMA distance + argmin ----------
// grid (128, 64): 128x128 tile of rows x codes. 3-pass bf16 split GEMM.
// LDS cell swizzle: row r's 16B cell p holds global segment p ^ ((r>>1)&3).
// Per-8-lane ds_read_b128 beats then touch all 8 bank-groups (was 2 -> 4-way conflict).
__global__ __launch_bounds__(256, 4) void dist_mfma_k(
    const ushort* __restrict__ xh, const ushort* __restrict__ xl,
    const ushort* __restrict__ ch, const ushort* __restrict__ cl,
    const float* __restrict__ e2, ull* __restrict__ packed)
{
    __shared__ ushort Ah[128 * 32];
    __shared__ ushort Al[128 * 32];
    __shared__ ushort Bh[128 * 32];
    __shared__ ushort Bl[128 * 32];

    const int tid  = threadIdx.x;
    const int lane = tid & 63;
    const int w    = tid >> 6;
    const int wm   = w >> 1, wn = w & 1;
    const int row0 = blockIdx.x * 128;
    const int col0 = blockIdx.y * 128;

    floatx4 acc[4][4];
#pragma unroll
    for (int m = 0; m < 4; ++m)
#pragma unroll
        for (int n = 0; n < 4; ++n) acc[m][n] = (floatx4){0.f, 0.f, 0.f, 0.f};

    // staging chunk map: chunk c (0..511) -> row c>>2, LDS cell c&3 at lds off c*8;
    // global segment fetched = (c&3) ^ ((c>>3)&3)  [the swizzle]
    const int c0 = tid, c1 = tid + 256;
    const int r0c = c0 >> 2, s0c = (((c0 & 3) ^ ((c0 >> 3) & 3))) * 8;
    const int r1c = c1 >> 2, s1c = (((c1 & 3) ^ ((c1 >> 3) & 3))) * 8;
    const int ga0 = (row0 + r0c) * DIM + s0c;   // + dk
    const int ga1 = (row0 + r1c) * DIM + s1c;
    const int gb0 = (col0 + r0c) * DIM + s0c;
    const int gb1 = (col0 + r1c) * DIM + s1c;
    const int l0 = c0 * 8, l1 = c1 * 8;

    // fragment base: row (lane&15), cell (lane>>4) ^ ((lane>>1)&3)
    const int fr = (lane & 15) * 32 + (((lane >> 4) ^ ((lane >> 1) & 3)) * 8);

    for (int kk = 0; kk < 16; ++kk) {
        const int dk = kk * 32;
        __syncthreads();
        gld16(&xh[ga0 + dk], &Ah[l0]);  gld16(&xh[ga1 + dk], &Ah[l1]);
        gld16(&xl[ga0 + dk], &Al[l0]);  gld16(&xl[ga1 + dk], &Al[l1]);
        gld16(&ch[gb0 + dk], &Bh[l0]);  gld16(&ch[gb1 + dk], &Bh[l1]);
        gld16(&cl[gb0 + dk], &Bl[l0]);  gld16(&cl[gb1 + dk], &Bl[l1]);
        __syncthreads();

        short8 ah[4], al[4], bh[4], bl[4];
#pragma unroll
        for (int m = 0; m < 4; ++m) {
            const int o = (wm * 64 + m * 16) * 32 + fr;
            ah[m] = *(const short8*)&Ah[o];
            al[m] = *(const short8*)&Al[o];
        }
#pragma unroll
        for (int n = 0; n < 4; ++n) {
            const int o = (wn * 64 + n * 16) * 32 + fr;
            bh[n] = *(const short8*)&Bh[o];
            bl[n] = *(const short8*)&Bl[o];
        }
#pragma unroll
        for (int m = 0; m < 4; ++m)
#pragma unroll
            for (int n = 0; n < 4; ++n) {
                acc[m][n] = __builtin_amdgcn_mfma_f32_16x16x32_bf16(ah[m], bh[n], acc[m][n], 0, 0, 0);
                acc[m][n] = __builtin_amdgcn_mfma_f32_16x16x32_bf16(ah[m], bl[n], acc[m][n], 0, 0, 0);
                acc[m][n] = __builtin_amdgcn_mfma_f32_16x16x32_bf16(al[m], bh[n], acc[m][n], 0, 0, 0);
            }
    }

    // epilogue: v = e2[c] - 2*dot ; argmin with first-occurrence tie-break
    float e2v[4];
    int   cidx[4];
#pragma unroll
    for (int n = 0; n < 4; ++n) {
        cidx[n] = col0 + wn * 64 + n * 16 + (lane & 15);
        e2v[n]  = e2[cidx[n]];
    }
#pragma unroll
    for (int m = 0; m < 4; ++m) {
#pragma unroll
        for (int r = 0; r < 4; ++r) {
            float bv = INFINITY; int bi = 0x7fffffff;
#pragma unroll
            for (int n = 0; n < 4; ++n) {        // ascending code order
                float v = e2v[n] - 2.f * acc[m][n][r];
                if (v < bv) { bv = v; bi = cidx[n]; }
            }
#pragma unroll
            for (int mk = 1; mk < 16; mk <<= 1) {  // 16-lane butterfly (same quad group)
                float ov = __shfl_xor(bv, mk, 64);
                int   oi = __shfl_xor(bi, mk, 64);
                if (ov < bv || (ov == bv && oi < bi)) { bv = ov; bi = oi; }
            }
            if ((lane & 15) == 0) {
                int grow = row0 + wm * 64 + m * 16 + (lane >> 4) * 4 + r;
                ull pack = ((ull)fmap(bv) << 32) | (unsigned)bi;
                atomicMin(&packed[grow], pack);
            }
        }
    }
}

// ---------- fused merge + gather + loss partials ----------
// unpack argmin, write indices/min_dist, gather codebook row, partial sum (x-q)^2
__global__ __launch_bounds__(256) void gather_loss_k(const float* __restrict__ x,
    const float* __restrict__ cb, const ull* __restrict__ packed,
    const float* __restrict__ x2, float* __restrict__ outq,
    float* __restrict__ out_idx, float* __restrict__ out_mind,
    float* __restrict__ partials)
{
    __shared__ float ps[4];
    int gid  = blockIdx.x * blockDim.x + threadIdx.x;
    int row  = gid >> 6;
    int lane = threadIdx.x & 63;
    int w    = threadIdx.x >> 6;
    float s = 0.f;
    if (row < NROWS) {
        ull p = packed[row];                 // same-address within wave: broadcast
        int k = (int)(p & 0xffffffffull);
        if (lane == 0) {
            out_idx[row]  = (float)k;
            out_mind[row] = x2[row] + funmap((unsigned)(p >> 32));
        }
        const float4* q  = (const float4*)(cb + (size_t)k * DIM);
        const float4* xr = (const float4*)(x + (size_t)row * DIM);
        float4* o = (float4*)(outq + (size_t)row * DIM);
#pragma unroll
        for (int i = lane; i < DIM / 4; i += 64) {
            float4 qv = q[i], xv = xr[i];
            o[i] = qv;
            float dx = xv.x - qv.x, dy = xv.y - qv.y;
            float dz = xv.z - qv.z, dw = xv.w - qv.w;
            s += dx * dx + dy * dy + dz * dz + dw * dw;
        }
    }
#pragma unroll
    for (int off = 32; off > 0; off >>= 1) s += __shfl_down(s, off, 64);
    if (lane == 0) ps[w] = s;
    __syncthreads();
    if (threadIdx.x == 0) partials[blockIdx.x] = ps[0] + ps[1] + ps[2] + ps[3];
}

// ---------- final reduction of partials -> loss outputs ----------
__global__ __launch_bounds__(256) void finalize_k(const float* __restrict__ partials,
    float* __restrict__ out_loss, float* __restrict__ out_commit)
{
    __shared__ float ps[4];
    int t = threadIdx.x, lane = t & 63, w = t >> 6;
    float s = 0.f;
#pragma unroll
    for (int i = 0; i < NPART / 256; ++i) s += partials[t + 256 * i];
#pragma unroll
    for (int off = 32; off > 0; off >>= 1) s += __shfl_down(s, off, 64);
    if (lane == 0) ps[w] = s;
    __syncthreads();
    if (t == 0) {
        float tot = ps[0] + ps[1] + ps[2] + ps[3];
        *out_loss   = 0.25f * tot + tot;
        *out_commit = tot;
    }
}

// ================= fallback (fp32 path, small ws) =================
#define BM 64
#define BN 64
#define BK 32
#define KSPLIT 4
#define KPER (NUM_EMB / KSPLIT)
#define NCT (KPER / BN)

__global__ __launch_bounds__(256) void rowsumsq_k(const float* __restrict__ a,
                                                  float* __restrict__ out, int nrows)
{
    int gid  = blockIdx.x * blockDim.x + threadIdx.x;
    int row  = gid >> 6;
    int lane = threadIdx.x & 63;
    if (row >= nrows) return;
    const float4* r = (const float4*)(a + (size_t)row * DIM);
    float s = 0.f;
#pragma unroll
    for (int i = lane; i < DIM / 4; i += 64) {
        float4 v = r[i];
        s += v.x * v.x + v.y * v.y + v.z * v.z + v.w * v.w;
    }
#pragma unroll
    for (int off = 32; off > 0; off >>= 1) s += __shfl_down(s, off, 64);
    if (lane == 0) out[row] = s;
}

__global__ __launch_bounds__(256) void dist_argmin_old_k(const float* __restrict__ x,
    const float* __restrict__ cb, const float* __restrict__ e2,
    float* __restrict__ part_m, int* __restrict__ part_i)
{
    __shared__ __align__(16) float As[BK][BM + 4];
    __shared__ __align__(16) float Bs[BK][BN + 4];
    __shared__ float redv[BM][16];
    __shared__ int   redi[BM][16];

    const int row0 = blockIdx.x * BM;
    const int ks   = blockIdx.y;
    const int cbeg = ks * KPER;
    const int t    = threadIdx.x;
    const int tx   = t & 15;
    const int ty   = t >> 4;
    const int ld_d = t & 31;
    const int ld_r = t >> 5;

    float minm[4]; int mini[4];
#pragma unroll
    for (int i = 0; i < 4; ++i) { minm[i] = INFINITY; mini[i] = 0; }

    for (int ct = 0; ct < NCT; ++ct) {
        const int c0 = cbeg + ct * BN;
        float acc[4][4];
#pragma unroll
        for (int i = 0; i < 4; ++i)
#pragma unroll
            for (int j = 0; j < 4; ++j) acc[i][j] = 0.f;
        for (int dc = 0; dc < DIM; dc += BK) {
#pragma unroll
            for (int rr = 0; rr < BM; rr += 8)
                As[ld_d][ld_r + rr] = x[(size_t)(row0 + ld_r + rr) * DIM + dc + ld_d];
#pragma unroll
            for (int rr = 0; rr < BN; rr += 8)
                Bs[ld_d][ld_r + rr] = cb[(size_t)(c0 + ld_r + rr) * DIM + dc + ld_d];
            __syncthreads();
#pragma unroll
            for (int d = 0; d < BK; ++d) {
                float4 av = *(const float4*)&As[d][4 * ty];
                float4 bv = *(const float4*)&Bs[d][4 * tx];
                acc[0][0] += av.x * bv.x; acc[0][1] += av.x * bv.y;
                acc[0][2] += av.x * bv.z; acc[0][3] += av.x * bv.w;
                acc[1][0] += av.y * bv.x; acc[1][1] += av.y * bv.y;
                acc[1][2] += av.y * bv.z; acc[1][3] += av.y * bv.w;
                acc[2][0] += av.z * bv.x; acc[2][1] += av.z * bv.y;
                acc[2][2] += av.z * bv.z; acc[2][3] += av.z * bv.w;
                acc[3][0] += av.w * bv.x; acc[3][1] += av.w * bv.y;
                acc[3][2] += av.w * bv.z; acc[3][3] += av.w * bv.w;
            }
            __syncthreads();
        }
#pragma unroll
        for (int j = 0; j < 4; ++j) {
            const int c = c0 + 4 * tx + j;
            const float e = e2[c];
#pragma unroll
            for (int i = 0; i < 4; ++i) {
                float m = e - 2.f * acc[i][j];
                if (m < minm[i]) { minm[i] = m; mini[i] = c; }
            }
        }
    }
#pragma unroll
    for (int i = 0; i < 4; ++i) {
        redv[4 * ty + i][tx] = minm[i];
        redi[4 * ty + i][tx] = mini[i];
    }
    __syncthreads();
    if (t < BM) {
        float bm = INFINITY; int bi = 0;
#pragma unroll
        for (int c = 0; c < 16; ++c) {
            float v = redv[t][c];
            if (v < bm) { bm = v; bi = redi[t][c]; }
        }
        part_m[(size_t)(row0 + t) * KSPLIT + ks] = bm;
        part_i[(size_t)(row0 + t) * KSPLIT + ks] = bi;
    }
}

__global__ __launch_bounds__(256) void merge_pack_k(const float* __restrict__ part_m,
    const int* __restrict__ part_i, ull* __restrict__ packed)
{
    int row = blockIdx.x * blockDim.x + threadIdx.x;
    if (row >= NROWS) return;
    float bm = INFINITY; int bi = 0;
#pragma unroll
    for (int s = 0; s < KSPLIT; ++s) {
        float v = part_m[(size_t)row * KSPLIT + s];
        if (v < bm) { bm = v; bi = part_i[(size_t)row * KSPLIT + s]; }
    }
    packed[row] = ((ull)fmap(bm) << 32) | (unsigned)bi;
}

// ================= launch =================
extern "C" void kernel_launch(void* const* d_in, const int* in_sizes, int n_in,
                              void* d_out, int out_size, void* d_ws, size_t ws_size,
                              hipStream_t stream)
{
    const float* x  = (const float*)d_in[0];   // [16384, 512]
    const float* cb = (const float*)d_in[1];   // [8192, 512]
    float* out = (float*)d_out;

    float* outq       = out;
    float* out_loss   = out + 8388608;
    float* out_idx    = out + 8388609;
    float* out_mind   = out + 8388609 + 16384;
    float* out_commit = out + 8388609 + 2 * 16384;

    char* ws = (char*)d_ws;
    float* e2      = (float*)ws;   ws += NUM_EMB * 4;
    float* x2      = (float*)ws;   ws += NROWS * 4;
    ull*   packed  = (ull*)ws;     ws += NROWS * 8;
    float* partials= (float*)ws;   ws += NPART * 4;
    ushort* xh = (ushort*)ws;      ws += (size_t)NROWS * DIM * 2;
    ushort* xl = (ushort*)ws;      ws += (size_t)NROWS * DIM * 2;
    ushort* ch = (ushort*)ws;      ws += (size_t)NUM_EMB * DIM * 2;
    ushort* cl = (ushort*)ws;      ws += (size_t)NUM_EMB * DIM * 2;
    size_t need_fast = (size_t)(ws - (char*)d_ws);

    if (ws_size >= need_fast) {
        split_rss_k<<<NROWS / 4, 256, 0, stream>>>(x, xh, xl, x2, packed, NROWS);
        split_rss_k<<<NUM_EMB / 4, 256, 0, stream>>>(cb, ch, cl, e2, (ull*)0, NUM_EMB);
        dim3 grid(NROWS / 128, NUM_EMB / 128);
        dist_mfma_k<<<grid, 256, 0, stream>>>(xh, xl, ch, cl, e2, packed);
    } else {
        // fallback: fp32 path (small ws)
        rowsumsq_k<<<NUM_EMB / 4, 256, 0, stream>>>(cb, e2, NUM_EMB);
        rowsumsq_k<<<NROWS / 4, 256, 0, stream>>>(x, x2, NROWS);
        float* pm = (float*)((char*)d_ws + NUM_EMB * 4 + NROWS * 4 + NROWS * 8 + NPART * 4);
        int*   pi = (int*)(pm + (size_t)NROWS * KSPLIT);
        dim3 grid(NROWS / BM, KSPLIT);
        dist_argmin_old_k<<<grid, 256, 0, stream>>>(x, cb, e2, pm, pi);
        merge_pack_k<<<NROWS / 256, 256, 0, stream>>>(pm, pi, packed);
    }

    gather_loss_k<<<NROWS / 4, 256, 0, stream>>>(x, cb, packed, x2, outq,
                                                 out_idx, out_mind, partials);
    finalize_k<<<1, 256, 0, stream>>>(partials, out_loss, out_commit);
}